// Round 20
// baseline (146.729 us; speedup 1.0000x reference)
//
#include <hip/hip_runtime.h>
#include <hip/hip_bf16.h>

#define BB 8
#define CC 512
#define TT 1024
#define HH 8
#define HD 64
#define CLIPW 4
#define NCOUT 512

using bf16 = __hip_bfloat16;
typedef __bf16 bf16x8_t __attribute__((ext_vector_type(8)));
typedef __bf16 bf16x4_t __attribute__((ext_vector_type(4)));
typedef __bf16 bf16x2_t __attribute__((ext_vector_type(2)));
typedef float f32x4_t __attribute__((ext_vector_type(4)));

// ===========================================================================
// prep_w: W (512x512 fp32, row-major [o][c]) -> A-frag bf16 layout
// ===========================================================================
__global__ __launch_bounds__(256) void prep_w(
    const float* __restrict__ Wq, const float* __restrict__ Wk,
    const float* __restrict__ Wv, const float* __restrict__ Wp,
    bf16* __restrict__ wqf, bf16* __restrict__ wkf,
    bf16* __restrict__ wvf, bf16* __restrict__ wpf) {
  const int which = blockIdx.y;
  const float* W = (which == 0) ? Wq : (which == 1) ? Wk : (which == 2) ? Wv : Wp;
  bf16* F = (which == 0) ? wqf : (which == 1) ? wkf : (which == 2) ? wvf : wpf;
  const int gid = blockIdx.x * 256 + threadIdx.x;
  const int l = gid & 63;
  const int fid = gid >> 6;            // ot*16 + ct, 0..511
  const int ct = fid & 15, ot = fid >> 4;
  const int sl = l & 15, g = l >> 4;
  const float* src = W + (size_t)(ot * 16 + sl) * CC + ct * 32 + g * 8;
  bf16x8_t p;
#pragma unroll
  for (int j = 0; j < 8; ++j) p[j] = (__bf16)src[j];
  *(bf16x8_t*)(F + (size_t)fid * 512 + l * 8) = p;
}

// ===========================================================================
// prep_x: X [b][c][t] fp32 -> B-frag bf16 layout. 1D grid, b = fi&7 (XCD).
// ===========================================================================
__global__ __launch_bounds__(256) void prep_x(
    const float* __restrict__ X, bf16* __restrict__ xfrag) {
  __shared__ float Xs[32][72];
  const int fi = blockIdx.x;
  const int b = fi & 7;
  const int k = fi >> 3;               // 0..255
  const int ct = k & 15, tq = k >> 4;
  const int c0 = ct * 32, t0 = tq * 64;
  const int tid = threadIdx.x;
  {
    const int ci = tid >> 4;           // 0..15
    const int t4 = (tid & 15) * 4;
#pragma unroll
    for (int cp = 0; cp < 2; ++cp) {
      const int c = cp * 16 + ci;
      const float4 x4 = *(const float4*)&X[((size_t)b * CC + c0 + c) * TT + t0 + t4];
      *(float4*)&Xs[c][t4] = x4;
    }
  }
  __syncthreads();
  const int l = tid & 63, fr = tid >> 6;   // fr = local tt (0..3)
  const int sl = l & 15, g = l >> 4;
  bf16x8_t p;
#pragma unroll
  for (int j = 0; j < 8; ++j) p[j] = (__bf16)Xs[g * 8 + j][fr * 16 + sl];
  *(bf16x8_t*)(xfrag + (((size_t)b * 64 + tq * 4 + fr) * 16 + ct) * 512 + l * 8) = p;
}

// ===========================================================================
// gemm_qkv2: zero-LDS main loop from frag operands. 1D grid, b = fi&7 (XCD).
// ===========================================================================
__global__ __launch_bounds__(256) void gemm_qkv2(
    const bf16* __restrict__ xfrag,
    const bf16* __restrict__ wqf, const bf16* __restrict__ wkf,
    const bf16* __restrict__ wvf,
    const float* __restrict__ bq, const float* __restrict__ bk,
    const float* __restrict__ bv,
    bf16* __restrict__ qfrag, bf16* __restrict__ kfrag, bf16* __restrict__ vfrag) {
  __shared__ __align__(16) float Cs[64 * 68];
  const int fi = blockIdx.x;
  const int b  = fi & 7;
  const int k2 = fi >> 3;              // 0..383 = 24 y * 16 x
  const int y  = k2 % 24;
  const int xb = k2 / 24;
  const int m  = y >> 3;
  const int o0 = (y & 7) * 64;
  const int t0 = xb * 64;
  const bf16* WF = (m == 0) ? wqf : (m == 1) ? wkf : wvf;
  const float* bias = (m == 0) ? bq : (m == 1) ? bk : bv;

  const int tid = threadIdx.x;
  const int w = tid >> 6, l = tid & 63, g = l >> 4, sl = l & 15;
  const int wr = w >> 1, wc = w & 1;
  const int ot0 = (o0 >> 4) + wr * 2;
  const int tt0 = (t0 >> 4) + wc * 2;

  f32x4_t acc[2][2] = {};
#pragma unroll 4
  for (int ct = 0; ct < 16; ++ct) {
    bf16x8_t a[2], bb[2];
#pragma unroll
    for (int mm = 0; mm < 2; ++mm)
      a[mm] = *(const bf16x8_t*)(WF + ((size_t)(ot0 + mm) * 16 + ct) * 512 + l * 8);
#pragma unroll
    for (int nn = 0; nn < 2; ++nn)
      bb[nn] = *(const bf16x8_t*)(xfrag + (((size_t)b * 64 + tt0 + nn) * 16 + ct) * 512 + l * 8);
#pragma unroll
    for (int mm = 0; mm < 2; ++mm)
#pragma unroll
      for (int nn = 0; nn < 2; ++nn)
        acc[mm][nn] = __builtin_amdgcn_mfma_f32_16x16x32_bf16(a[mm], bb[nn], acc[mm][nn], 0, 0, 0);
  }

#pragma unroll
  for (int mm = 0; mm < 2; ++mm)
#pragma unroll
    for (int nn = 0; nn < 2; ++nn)
#pragma unroll
      for (int r = 0; r < 4; ++r)
        Cs[(wr * 32 + mm * 16 + 4 * g + r) * 68 + wc * 32 + nn * 16 + sl] = acc[mm][nn][r];
  __syncthreads();

  const int hh2 = o0 >> 6;
  const int bh  = b * HH + hh2;
  const int fr = tid >> 6, l2 = tid & 63;
  const int sl2 = l2 & 15, g2 = l2 >> 4;
  if (m == 0) {
#pragma unroll
    for (int kh = 0; kh < 2; ++kh) {
      bf16x8_t p;
#pragma unroll
      for (int j = 0; j < 8; ++j) {
        const int d = kh * 32 + g2 * 8 + j;
        p[j] = (__bf16)(Cs[d * 68 + fr * 16 + sl2] + bias[o0 + d]);
      }
      *(bf16x8_t*)(qfrag + (((size_t)bh * 64 + (t0 >> 4) + fr) * 2 + kh) * 512 + l2 * 8) = p;
    }
  } else if (m == 1) {
    bf16* dpf = kfrag + (((size_t)bh * 64 + (t0 >> 4) + fr) * 2) * 512;
#pragma unroll
    for (int half = 0; half < 2; ++half) {
      bf16x8_t p;
#pragma unroll
      for (int j = 0; j < 8; ++j) {
        const int d = half * 32 + g2 * 8 + j;
        p[j] = (__bf16)(Cs[d * 68 + fr * 16 + sl2] + bias[o0 + d]);
      }
      *(bf16x8_t*)(dpf + half * 512 + l2 * 8) = p;
    }
  } else {
    const int dt = fr;                  // 0..3
    const int d  = dt * 16 + sl2;
    const float bv_ = bias[o0 + d];
#pragma unroll
    for (int i2p = 0; i2p < 2; ++i2p) {
      const int i2 = (t0 >> 5) + i2p;
      bf16x8_t p;
#pragma unroll
      for (int j = 0; j < 8; ++j) {
        const int tloc = i2p * 32 + g2 * 8 + j;
        p[j] = (__bf16)(Cs[d * 68 + tloc] + bv_);
      }
      *(bf16x8_t*)(vfrag + ((((size_t)bh * 32 + i2) * 4 + dt) * 64 + l2) * 8) = p;
    }
  }
}

// ===========================================================================
// gemm_out2: zero-LDS main loop; 1D grid, b = fi&7 (XCD-resident attnfrag).
// ===========================================================================
__global__ __launch_bounds__(256) void gemm_out2(
    const bf16* __restrict__ attnfrag, const bf16* __restrict__ wpf,
    const float* __restrict__ bp, float* __restrict__ out) {
  __shared__ __align__(16) float Cs[64 * 68];
  const int fi = blockIdx.x;
  const int b  = fi & 7;
  const int k2 = fi >> 3;              // 0..127 = 8 o * 16 t
  const int o0 = (k2 & 7) * 64;
  const int t0 = (k2 >> 3) * 64;
  const int tid = threadIdx.x;
  const int w = tid >> 6, l = tid & 63, g = l >> 4, sl = l & 15;
  const int wr = w >> 1, wc = w & 1;
  const int ot0 = (o0 >> 4) + wr * 2;
  const int tt0 = (t0 >> 4) + wc * 2;

  f32x4_t acc[2][2] = {};
#pragma unroll 4
  for (int ct = 0; ct < 16; ++ct) {
    bf16x8_t a[2], bb[2];
#pragma unroll
    for (int mm = 0; mm < 2; ++mm)
      a[mm] = *(const bf16x8_t*)(wpf + ((size_t)(ot0 + mm) * 16 + ct) * 512 + l * 8);
#pragma unroll
    for (int nn = 0; nn < 2; ++nn)
      bb[nn] = *(const bf16x8_t*)(attnfrag + (((size_t)b * 64 + tt0 + nn) * 16 + ct) * 512 + l * 8);
#pragma unroll
    for (int mm = 0; mm < 2; ++mm)
#pragma unroll
      for (int nn = 0; nn < 2; ++nn)
        acc[mm][nn] = __builtin_amdgcn_mfma_f32_16x16x32_bf16(a[mm], bb[nn], acc[mm][nn], 0, 0, 0);
  }

#pragma unroll
  for (int mm = 0; mm < 2; ++mm)
#pragma unroll
    for (int nn = 0; nn < 2; ++nn)
#pragma unroll
      for (int r = 0; r < 4; ++r)
        Cs[(wr * 32 + mm * 16 + 4 * g + r) * 68 + wc * 32 + nn * 16 + sl] = acc[mm][nn][r];
  __syncthreads();

  const int o = tid >> 2, tq = tid & 3;
  const float bv_ = bp[o0 + o];
  float* dp = out + ((size_t)b * NCOUT + o0 + o) * TT + t0 + tq * 16;
#pragma unroll
  for (int i4 = 0; i4 < 4; ++i4) {
    f32x4_t v = *(const f32x4_t*)&Cs[o * 68 + tq * 16 + i4 * 4];
    v[0] += bv_; v[1] += bv_; v[2] += bv_; v[3] += bv_;
    *(f32x4_t*)(dp + i4 * 4) = v;
  }
}

// ===========================================================================
// attn v16: same algorithm as v12 but 8 waves x 128-s slices (512 threads)
// -> 32 waves/CU (vs 16) at unchanged LDS content. eL[128 rows][132] where
// row=(w*16+ql) holds q-row ql's s-slice [w*128, w*128+128). bandv/invL are
// written redundantly by every wave (identical values -> benign race, no
// barrier, same-wave ordering guarantees own visibility).
// ===========================================================================
__global__ __launch_bounds__(512, 4) void attn_v16(
    const bf16* __restrict__ qfrag, const bf16* __restrict__ kfrag,
    const bf16* __restrict__ vfrag,
    const float* __restrict__ wK, const float* __restrict__ wV,
    float* __restrict__ align_out, bf16* __restrict__ attnfrag) {
  const int fi   = blockIdx.x;
  const int xcd  = fi & 7;
  const int k2   = fi >> 3;
  const int bh   = ((k2 >> 6) << 3) + xcd;
  const int qblk = k2 & 63;
  const int b = bh >> 3, h = bh & 7;
  const int q0 = qblk * 16;

  const int tid = threadIdx.x;
  const int w = tid >> 6, l = tid & 63, g = l >> 4, ql = l & 15;
  const int qabs  = q0 + ql;
  const int sbase = w * 128;

  __shared__ __align__(16) char smem[37440];
  __bf16* eL      = (__bf16*)smem;               // [128][132] bf16 = 33792 B
  float* obuf     = (float*)smem;                // overlay [4][1088] = 17408 B
  float* stg      = (float*)(smem + 17408);      // overlay [64][17] fp32
  float* bandv16  = (float*)(smem + 33792);      // [16][12] = 768 B (shared)
  float* bandP    = (float*)(smem + 34560);      // [16][36] = 2304 B
  float* redbuf   = (float*)(smem + 36864);      // [8][16] = 512 B
  float* invL     = (float*)(smem + 37376);      // 16 floats

  for (int i = tid; i < 576; i += 512) bandP[i] = 0.f;

  // Q B-frags (contiguous 1KB wave loads; identical for all waves)
  const bf16* qfb = qfrag + (((size_t)bh * 64 + (q0 >> 4)) * 2) * 512 + l * 8;
  const bf16x8_t qa0 = *(const bf16x8_t*)qfb;
  const bf16x8_t qa1 = *(const bf16x8_t*)(qfb + 512);

  // band-K: every wave computes identical D[j][q]; redundant benign writes.
  {
    const int j = (ql < 9) ? ql : 0;
    const float* wkr = wK + j * HD + g * 8;
    const f32x4_t w0 = *(const f32x4_t*)wkr;
    const f32x4_t w1 = *(const f32x4_t*)(wkr + 4);
    const f32x4_t w2 = *(const f32x4_t*)(wkr + 32);
    const f32x4_t w3 = *(const f32x4_t*)(wkr + 36);
    bf16x8_t ka0, ka1;
#pragma unroll
    for (int i = 0; i < 4; ++i) {
      ka0[i] = (__bf16)w0[i]; ka0[4 + i] = (__bf16)w1[i];
      ka1[i] = (__bf16)w2[i]; ka1[4 + i] = (__bf16)w3[i];
    }
    f32x4_t bacc = {0.f, 0.f, 0.f, 0.f};
    bacc = __builtin_amdgcn_mfma_f32_16x16x32_bf16(ka0, qa0, bacc, 0, 0, 0);
    bacc = __builtin_amdgcn_mfma_f32_16x16x32_bf16(ka1, qa1, bacc, 0, 0, 0);
#pragma unroll
    for (int r = 0; r < 4; ++r)
      if (4 * g + r < 9) bandv16[ql * 12 + 4 * g + r] = bacc[r];
  }

  // ---- pass 1: QK + exp over this wave's 8 s-tiles ----
  float ls = 0.f;
  bf16x4_t stash[8];
  const int erow = (w * 16 + ql) * 132;
  const bf16* kfb = kfrag + (((size_t)bh * 64 + w * 8) * 2) * 512 + l * 8;
#pragma unroll
  for (int st = 0; st < 8; ++st) {
    const bf16x8_t k0 = *(const bf16x8_t*)(kfb + (size_t)st * 1024);
    const bf16x8_t k1 = *(const bf16x8_t*)(kfb + (size_t)st * 1024 + 512);
    f32x4_t a = {0.f, 0.f, 0.f, 0.f};
    a = __builtin_amdgcn_mfma_f32_16x16x32_bf16(k0, qa0, a, 0, 0, 0);
    a = __builtin_amdgcn_mfma_f32_16x16x32_bf16(k1, qa1, a, 0, 0, 0);
    const int s0t = sbase + st * 16;
    const bool near = (s0t + 15 >= q0 - CLIPW) && (s0t <= q0 + 15 + CLIPW);
#pragma unroll
    for (int r = 0; r < 4; ++r) {
      float x = a[r];
      if (near) {
        const int delta = s0t + 4 * g + r - qabs;
        if ((unsigned)(delta + CLIPW) <= 2 * CLIPW)
          x += bandv16[ql * 12 + delta + CLIPW];
      }
      const float e = __expf(x * 0.125f);
      stash[st][r] = (__bf16)e;
      ls += e;
    }
    *(bf16x4_t*)&eL[erow + st * 16 + 4 * g] = stash[st];
  }
  ls += __shfl_xor(ls, 16);
  ls += __shfl_xor(ls, 32);
  if (l < 16) redbuf[w * 16 + ql] = ls;
  __syncthreads();
  float lsum = 0.f;
#pragma unroll
  for (int k = 0; k < 8; ++k) lsum += redbuf[k * 16 + ql];
  const float inv = 1.0f / lsum;
  if (l < 16) invL[l] = inv;   // redundant identical writes across waves

  // ---- bandP extraction (predicated, mostly skipped) ----
#pragma unroll
  for (int st = 0; st < 8; ++st) {
    const int s0t = sbase + st * 16;
    const bool near = (s0t + 15 >= q0 - CLIPW) && (s0t <= q0 + 15 + CLIPW);
    if (near) {
#pragma unroll
      for (int r = 0; r < 4; ++r) {
        const int delta = s0t + 4 * g + r - qabs;
        if ((unsigned)(delta + CLIPW) <= 2 * CLIPW)
          bandP[ql * 36 + delta + CLIPW] = (float)stash[st][r] * inv;
      }
    }
  }

  // ---- pass 2: PV (4 i2 slices) + interleaved dense NT stores ----
  f32x4_t oacc[4] = {};
  const bf16* vfb = vfrag + (((size_t)bh * 32 + w * 4) * 4) * 512 + l * 8;
  const int lh = l >> 5;        // half-wave selector (2 q-rows per store iter)
  const int l32 = l & 31;
  float* abase = align_out + ((size_t)bh * TT + q0) * TT + sbase;
#pragma unroll
  for (int i2l = 0; i2l < 4; ++i2l) {
    const bf16x8_t pb = *(const bf16x8_t*)&eL[erow + i2l * 32 + 8 * g];
#pragma unroll
    for (int dt = 0; dt < 4; ++dt) {
      const bf16x8_t va = *(const bf16x8_t*)(vfb + ((size_t)i2l * 4 + dt) * 512);
      oacc[dt] = __builtin_amdgcn_mfma_f32_16x16x32_bf16(va, pb, oacc[dt], 0, 0, 0);
    }
#pragma unroll
    for (int qq = 0; qq < 2; ++qq) {
      const int q = i2l * 4 + qq * 2 + lh;
      const float iq = invL[q];
      const bf16x4_t e4 = *(const bf16x4_t*)&eL[(w * 16 + q) * 132 + l32 * 4];
      f32x4_t p4;
      p4[0] = (float)e4[0] * iq;
      p4[1] = (float)e4[1] * iq;
      p4[2] = (float)e4[2] * iq;
      p4[3] = (float)e4[3] * iq;
      __builtin_nontemporal_store(p4, (f32x4_t*)(abase + (size_t)q * TT + l32 * 4));
    }
  }
#pragma unroll
  for (int dt = 0; dt < 4; ++dt) {
    oacc[dt][0] *= inv; oacc[dt][1] *= inv;
    oacc[dt][2] *= inv; oacc[dt][3] *= inv;
  }

  // ---- 2-stage cross-wave PV reduce (obuf overlays eL after barrier) ----
  __syncthreads();
  if (w < 4) {
#pragma unroll
    for (int dt = 0; dt < 4; ++dt)
      *(f32x4_t*)&obuf[w * 1088 + ql * 68 + dt * 16 + 4 * g] = oacc[dt];
  }
  __syncthreads();
  if (w >= 4) {
#pragma unroll
    for (int dt = 0; dt < 4; ++dt) {
      f32x4_t cur = *(const f32x4_t*)&obuf[(w - 4) * 1088 + ql * 68 + dt * 16 + 4 * g];
      cur += oacc[dt];
      *(f32x4_t*)&obuf[(w - 4) * 1088 + ql * 68 + dt * 16 + 4 * g] = cur;
    }
  }
  __syncthreads();

  // ---- epilogue (wave 0): reduce + band-V MFMA + frag-layout attn store ----
  if (w == 0) {
    f32x4_t osum[4];
#pragma unroll
    for (int dt = 0; dt < 4; ++dt) {
      const int off = ql * 68 + dt * 16 + 4 * g;
      osum[dt] = *(const f32x4_t*)&obuf[off] + *(const f32x4_t*)&obuf[1088 + off] +
                 *(const f32x4_t*)&obuf[2176 + off] + *(const f32x4_t*)&obuf[3264 + off];
    }
    const f32x4_t b0 = *(const f32x4_t*)&bandP[ql * 36 + g * 8];
    const f32x4_t b1 = *(const f32x4_t*)&bandP[ql * 36 + g * 8 + 4];
    bf16x8_t pbb;
#pragma unroll
    for (int i = 0; i < 4; ++i) {
      pbb[i] = (__bf16)b0[i];
      pbb[4 + i] = (__bf16)b1[i];
    }
#pragma unroll
    for (int dt = 0; dt < 4; ++dt) {
      bf16x8_t wa;
#pragma unroll
      for (int jj = 0; jj < 8; ++jj) {
        const int j = g * 8 + jj;
        wa[jj] = (__bf16)((j < 9) ? wV[j * HD + dt * 16 + ql] : 0.f);
      }
      osum[dt] = __builtin_amdgcn_mfma_f32_16x16x32_bf16(wa, pbb, osum[dt], 0, 0, 0);
    }
#pragma unroll
    for (int dt = 0; dt < 4; ++dt)
#pragma unroll
      for (int r = 0; r < 4; ++r)
        stg[(dt * 16 + 4 * g + r) * 17 + ql] = osum[dt][r];
    // attnfrag write: ct global = h*2 + ctl, tt = q0>>4
#pragma unroll
    for (int ctl = 0; ctl < 2; ++ctl) {
      bf16x8_t p;
#pragma unroll
      for (int j = 0; j < 8; ++j)
        p[j] = (__bf16)stg[(ctl * 32 + g * 8 + j) * 17 + ql];
      *(bf16x8_t*)(attnfrag +
                   (((size_t)b * 64 + (q0 >> 4)) * 16 + h * 2 + ctl) * 512 + l * 8) = p;
    }
  }
}

extern "C" void kernel_launch(void* const* d_in, const int* in_sizes, int n_in,
                              void* d_out, int out_size, void* d_ws, size_t ws_size,
                              hipStream_t stream) {
  const float* X  = (const float*)d_in[0];
  const float* Wq = (const float*)d_in[1];
  const float* bq = (const float*)d_in[2];
  const float* Wk = (const float*)d_in[3];
  const float* bk = (const float*)d_in[4];
  const float* Wv = (const float*)d_in[5];
  const float* bv = (const float*)d_in[6];
  const float* Wp = (const float*)d_in[7];
  const float* bp = (const float*)d_in[8];
  const float* wK = (const float*)d_in[9];
  const float* wV = (const float*)d_in[10];

  float* out       = (float*)d_out;
  float* align_out = out + (size_t)BB * NCOUT * TT;

  const size_t SZ = (size_t)BB * HH * TT * HD;   // 4,194,304 elems (8 MB bf16)
  const size_t WF = 512 * 512;                    // 262,144 elems (0.5 MB bf16)
  bf16* qfrag    = (bf16*)d_ws;
  bf16* kfrag    = qfrag + SZ;
  bf16* vfrag    = qfrag + 2 * SZ;
  bf16* attnfrag = qfrag + 3 * SZ;
  bf16* xfrag    = qfrag + 4 * SZ;
  bf16* wqf      = qfrag + 5 * SZ;
  bf16* wkf      = wqf + WF;
  bf16* wvf      = wkf + WF;
  bf16* wpf      = wvf + WF;

  prep_w<<<dim3(128, 4), 256, 0, stream>>>(Wq, Wk, Wv, Wp, wqf, wkf, wvf, wpf);
  prep_x<<<dim3(2048), 256, 0, stream>>>(X, xfrag);
  gemm_qkv2<<<dim3(3072), 256, 0, stream>>>(
      xfrag, wqf, wkf, wvf, bq, bk, bv, qfrag, kfrag, vfrag);
  attn_v16<<<dim3(4096), 512, 0, stream>>>(
      qfrag, kfrag, vfrag, wK, wV, align_out, attnfrag);
  gemm_out2<<<dim3(1024), 256, 0, stream>>>(attnfrag, wpf, bp, out);
}

// Round 21
// 142.845 us; speedup vs baseline: 1.0272x; 1.0272x over previous
//
#include <hip/hip_runtime.h>
#include <hip/hip_bf16.h>

#define BB 8
#define CC 512
#define TT 1024
#define HH 8
#define HD 64
#define CLIPW 4
#define NCOUT 512

using bf16 = __hip_bfloat16;
typedef __bf16 bf16x8_t __attribute__((ext_vector_type(8)));
typedef __bf16 bf16x4_t __attribute__((ext_vector_type(4)));
typedef float f32x4_t __attribute__((ext_vector_type(4)));

// ===========================================================================
// prep_w: W (512x512 fp32, row-major [o][c]) -> A-frag bf16 layout
// ===========================================================================
__global__ __launch_bounds__(256) void prep_w(
    const float* __restrict__ Wq, const float* __restrict__ Wk,
    const float* __restrict__ Wv, const float* __restrict__ Wp,
    bf16* __restrict__ wqf, bf16* __restrict__ wkf,
    bf16* __restrict__ wvf, bf16* __restrict__ wpf) {
  const int which = blockIdx.y;
  const float* W = (which == 0) ? Wq : (which == 1) ? Wk : (which == 2) ? Wv : Wp;
  bf16* F = (which == 0) ? wqf : (which == 1) ? wkf : (which == 2) ? wvf : wpf;
  const int gid = blockIdx.x * 256 + threadIdx.x;
  const int l = gid & 63;
  const int fid = gid >> 6;            // ot*16 + ct, 0..511
  const int ct = fid & 15, ot = fid >> 4;
  const int sl = l & 15, g = l >> 4;
  const float* src = W + (size_t)(ot * 16 + sl) * CC + ct * 32 + g * 8;
  bf16x8_t p;
#pragma unroll
  for (int j = 0; j < 8; ++j) p[j] = (__bf16)src[j];
  *(bf16x8_t*)(F + (size_t)fid * 512 + l * 8) = p;
}

// ===========================================================================
// prep_x: X [b][c][t] fp32 -> B-frag bf16 layout. 1D grid, b = fi&7 (XCD).
// ===========================================================================
__global__ __launch_bounds__(256) void prep_x(
    const float* __restrict__ X, bf16* __restrict__ xfrag) {
  __shared__ float Xs[32][72];
  const int fi = blockIdx.x;
  const int b = fi & 7;
  const int k = fi >> 3;               // 0..255
  const int ct = k & 15, tq = k >> 4;
  const int c0 = ct * 32, t0 = tq * 64;
  const int tid = threadIdx.x;
  {
    const int ci = tid >> 4;           // 0..15
    const int t4 = (tid & 15) * 4;
#pragma unroll
    for (int cp = 0; cp < 2; ++cp) {
      const int c = cp * 16 + ci;
      const float4 x4 = *(const float4*)&X[((size_t)b * CC + c0 + c) * TT + t0 + t4];
      *(float4*)&Xs[c][t4] = x4;
    }
  }
  __syncthreads();
  const int l = tid & 63, fr = tid >> 6;   // fr = local tt (0..3)
  const int sl = l & 15, g = l >> 4;
  bf16x8_t p;
#pragma unroll
  for (int j = 0; j < 8; ++j) p[j] = (__bf16)Xs[g * 8 + j][fr * 16 + sl];
  *(bf16x8_t*)(xfrag + (((size_t)b * 64 + tq * 4 + fr) * 16 + ct) * 512 + l * 8) = p;
}

// ===========================================================================
// gemm_qkv2: zero-LDS main loop from frag operands. 1D grid, b = fi&7 (XCD)
// so xfrag(1MB/b) + wf(1.5MB) stay L2-resident per XCD.
// ===========================================================================
__global__ __launch_bounds__(256) void gemm_qkv2(
    const bf16* __restrict__ xfrag,
    const bf16* __restrict__ wqf, const bf16* __restrict__ wkf,
    const bf16* __restrict__ wvf,
    const float* __restrict__ bq, const float* __restrict__ bk,
    const float* __restrict__ bv,
    bf16* __restrict__ qfrag, bf16* __restrict__ kfrag, bf16* __restrict__ vfrag) {
  __shared__ __align__(16) float Cs[64 * 68];
  const int fi = blockIdx.x;
  const int b  = fi & 7;
  const int k2 = fi >> 3;              // 0..383 = 24 y * 16 x
  const int y  = k2 % 24;
  const int xb = k2 / 24;
  const int m  = y >> 3;
  const int o0 = (y & 7) * 64;
  const int t0 = xb * 64;
  const bf16* WF = (m == 0) ? wqf : (m == 1) ? wkf : wvf;
  const float* bias = (m == 0) ? bq : (m == 1) ? bk : bv;

  const int tid = threadIdx.x;
  const int w = tid >> 6, l = tid & 63, g = l >> 4, sl = l & 15;
  const int wr = w >> 1, wc = w & 1;
  const int ot0 = (o0 >> 4) + wr * 2;
  const int tt0 = (t0 >> 4) + wc * 2;

  f32x4_t acc[2][2] = {};
#pragma unroll 4
  for (int ct = 0; ct < 16; ++ct) {
    bf16x8_t a[2], bb[2];
#pragma unroll
    for (int mm = 0; mm < 2; ++mm)
      a[mm] = *(const bf16x8_t*)(WF + ((size_t)(ot0 + mm) * 16 + ct) * 512 + l * 8);
#pragma unroll
    for (int nn = 0; nn < 2; ++nn)
      bb[nn] = *(const bf16x8_t*)(xfrag + (((size_t)b * 64 + tt0 + nn) * 16 + ct) * 512 + l * 8);
#pragma unroll
    for (int mm = 0; mm < 2; ++mm)
#pragma unroll
      for (int nn = 0; nn < 2; ++nn)
        acc[mm][nn] = __builtin_amdgcn_mfma_f32_16x16x32_bf16(a[mm], bb[nn], acc[mm][nn], 0, 0, 0);
  }

#pragma unroll
  for (int mm = 0; mm < 2; ++mm)
#pragma unroll
    for (int nn = 0; nn < 2; ++nn)
#pragma unroll
      for (int r = 0; r < 4; ++r)
        Cs[(wr * 32 + mm * 16 + 4 * g + r) * 68 + wc * 32 + nn * 16 + sl] = acc[mm][nn][r];
  __syncthreads();

  const int hh2 = o0 >> 6;
  const int bh  = b * HH + hh2;
  const int fr = tid >> 6, l2 = tid & 63;
  const int sl2 = l2 & 15, g2 = l2 >> 4;
  if (m == 0) {
#pragma unroll
    for (int kh = 0; kh < 2; ++kh) {
      bf16x8_t p;
#pragma unroll
      for (int j = 0; j < 8; ++j) {
        const int d = kh * 32 + g2 * 8 + j;
        p[j] = (__bf16)(Cs[d * 68 + fr * 16 + sl2] + bias[o0 + d]);
      }
      *(bf16x8_t*)(qfrag + (((size_t)bh * 64 + (t0 >> 4) + fr) * 2 + kh) * 512 + l2 * 8) = p;
    }
  } else if (m == 1) {
    bf16* dpf = kfrag + (((size_t)bh * 64 + (t0 >> 4) + fr) * 2) * 512;
#pragma unroll
    for (int half = 0; half < 2; ++half) {
      bf16x8_t p;
#pragma unroll
      for (int j = 0; j < 8; ++j) {
        const int d = half * 32 + g2 * 8 + j;
        p[j] = (__bf16)(Cs[d * 68 + fr * 16 + sl2] + bias[o0 + d]);
      }
      *(bf16x8_t*)(dpf + half * 512 + l2 * 8) = p;
    }
  } else {
    const int dt = fr;                  // 0..3
    const int d  = dt * 16 + sl2;
    const float bv_ = bias[o0 + d];
#pragma unroll
    for (int i2p = 0; i2p < 2; ++i2p) {
      const int i2 = (t0 >> 5) + i2p;
      bf16x8_t p;
#pragma unroll
      for (int j = 0; j < 8; ++j) {
        const int tloc = i2p * 32 + g2 * 8 + j;
        p[j] = (__bf16)(Cs[d * 68 + tloc] + bv_);
      }
      *(bf16x8_t*)(vfrag + ((((size_t)bh * 32 + i2) * 4 + dt) * 64 + l2) * 8) = p;
    }
  }
}

// ===========================================================================
// gemm_out2: zero-LDS main loop; 1D grid, b = fi&7 (XCD-resident attnfrag).
// ===========================================================================
__global__ __launch_bounds__(256) void gemm_out2(
    const bf16* __restrict__ attnfrag, const bf16* __restrict__ wpf,
    const float* __restrict__ bp, float* __restrict__ out) {
  __shared__ __align__(16) float Cs[64 * 68];
  const int fi = blockIdx.x;
  const int b  = fi & 7;
  const int k2 = fi >> 3;              // 0..127 = 8 o * 16 t
  const int o0 = (k2 & 7) * 64;
  const int t0 = (k2 >> 3) * 64;
  const int tid = threadIdx.x;
  const int w = tid >> 6, l = tid & 63, g = l >> 4, sl = l & 15;
  const int wr = w >> 1, wc = w & 1;
  const int ot0 = (o0 >> 4) + wr * 2;
  const int tt0 = (t0 >> 4) + wc * 2;

  f32x4_t acc[2][2] = {};
#pragma unroll 4
  for (int ct = 0; ct < 16; ++ct) {
    bf16x8_t a[2], bb[2];
#pragma unroll
    for (int mm = 0; mm < 2; ++mm)
      a[mm] = *(const bf16x8_t*)(wpf + ((size_t)(ot0 + mm) * 16 + ct) * 512 + l * 8);
#pragma unroll
    for (int nn = 0; nn < 2; ++nn)
      bb[nn] = *(const bf16x8_t*)(attnfrag + (((size_t)b * 64 + tt0 + nn) * 16 + ct) * 512 + l * 8);
#pragma unroll
    for (int mm = 0; mm < 2; ++mm)
#pragma unroll
      for (int nn = 0; nn < 2; ++nn)
        acc[mm][nn] = __builtin_amdgcn_mfma_f32_16x16x32_bf16(a[mm], bb[nn], acc[mm][nn], 0, 0, 0);
  }

#pragma unroll
  for (int mm = 0; mm < 2; ++mm)
#pragma unroll
    for (int nn = 0; nn < 2; ++nn)
#pragma unroll
      for (int r = 0; r < 4; ++r)
        Cs[(wr * 32 + mm * 16 + 4 * g + r) * 68 + wc * 32 + nn * 16 + sl] = acc[mm][nn][r];
  __syncthreads();

  const int o = tid >> 2, tq = tid & 3;
  const float bv_ = bp[o0 + o];
  float* dp = out + ((size_t)b * NCOUT + o0 + o) * TT + t0 + tq * 16;
#pragma unroll
  for (int i4 = 0; i4 < 4; ++i4) {
    f32x4_t v = *(const f32x4_t*)&Cs[o * 68 + tq * 16 + i4 * 4];
    v[0] += bv_; v[1] += bv_; v[2] += bv_; v[3] += bv_;
    *(f32x4_t*)(dp + i4 * 4) = v;
  }
}

// ===========================================================================
// attn v12 (round-19 winner, unchanged): NT dense stores, no setprio,
// 4 waves x 256-s, 16 q-rows/block.
// ===========================================================================
__global__ __launch_bounds__(256, 4) void attn_v12(
    const bf16* __restrict__ qfrag, const bf16* __restrict__ kfrag,
    const bf16* __restrict__ vfrag,
    const float* __restrict__ wK, const float* __restrict__ wV,
    float* __restrict__ align_out, bf16* __restrict__ attnfrag) {
  const int fi   = blockIdx.x;
  const int xcd  = fi & 7;
  const int k2   = fi >> 3;
  const int bh   = ((k2 >> 6) << 3) + xcd;
  const int qblk = k2 & 63;
  const int b = bh >> 3, h = bh & 7;
  const int q0 = qblk * 16;

  const int tid = threadIdx.x;
  const int w = tid >> 6, l = tid & 63, g = l >> 4, ql = l & 15;
  const int qabs  = q0 + ql;
  const int sbase = w * 256;

  __shared__ __align__(16) char smem[39424];
  __bf16* eL    = (__bf16*)smem;
  float* bandv  = (float*)(smem + 33792);
  float* bandP  = (float*)(smem + 36864);
  float* redbuf = (float*)(smem + 39168);
  float* invL   = (float*)(smem + 33792);       // overlays bandv (free after p1)
  float* obuf   = (float*)smem;                 // overlay after barrier
  float* stg    = (float*)(smem + 17408);       // overlay epilogue

  for (int i = tid; i < 576; i += 256) bandP[i] = 0.f;

  // Q B-frags (contiguous 1KB wave loads)
  const bf16* qfb = qfrag + (((size_t)bh * 64 + (q0 >> 4)) * 2) * 512 + l * 8;
  const bf16x8_t qa0 = *(const bf16x8_t*)qfb;
  const bf16x8_t qa1 = *(const bf16x8_t*)(qfb + 512);

  // band-K: D[j][q] via mfma(A=wK rows, B=Q cols)
  {
    const int j = (ql < 9) ? ql : 0;
    const float* wkr = wK + j * HD + g * 8;
    const f32x4_t w0 = *(const f32x4_t*)wkr;
    const f32x4_t w1 = *(const f32x4_t*)(wkr + 4);
    const f32x4_t w2 = *(const f32x4_t*)(wkr + 32);
    const f32x4_t w3 = *(const f32x4_t*)(wkr + 36);
    bf16x8_t ka0, ka1;
#pragma unroll
    for (int i = 0; i < 4; ++i) {
      ka0[i] = (__bf16)w0[i]; ka0[4 + i] = (__bf16)w1[i];
      ka1[i] = (__bf16)w2[i]; ka1[4 + i] = (__bf16)w3[i];
    }
    f32x4_t bacc = {0.f, 0.f, 0.f, 0.f};
    bacc = __builtin_amdgcn_mfma_f32_16x16x32_bf16(ka0, qa0, bacc, 0, 0, 0);
    bacc = __builtin_amdgcn_mfma_f32_16x16x32_bf16(ka1, qa1, bacc, 0, 0, 0);
#pragma unroll
    for (int r = 0; r < 4; ++r)
      if (4 * g + r < 9) bandv[(w * 16 + ql) * 12 + 4 * g + r] = bacc[r];
  }

  // ---- pass 1: QK + exp; stash regs + k-major eL ----
  float ls = 0.f;
  bf16x4_t stash[16];
  const int erow = (w * 16 + ql) * 264;
  const bf16* kfb = kfrag + (((size_t)bh * 64 + w * 16) * 2) * 512 + l * 8;
#pragma unroll
  for (int st = 0; st < 16; ++st) {
    const bf16x8_t k0 = *(const bf16x8_t*)(kfb + (size_t)st * 1024);
    const bf16x8_t k1 = *(const bf16x8_t*)(kfb + (size_t)st * 1024 + 512);
    f32x4_t a = {0.f, 0.f, 0.f, 0.f};
    a = __builtin_amdgcn_mfma_f32_16x16x32_bf16(k0, qa0, a, 0, 0, 0);
    a = __builtin_amdgcn_mfma_f32_16x16x32_bf16(k1, qa1, a, 0, 0, 0);
    const int s0t = sbase + st * 16;
    const bool near = (s0t + 15 >= q0 - CLIPW) && (s0t <= q0 + 15 + CLIPW);
#pragma unroll
    for (int r = 0; r < 4; ++r) {
      float x = a[r];
      if (near) {
        const int delta = s0t + 4 * g + r - qabs;
        if ((unsigned)(delta + CLIPW) <= 2 * CLIPW)
          x += bandv[(w * 16 + ql) * 12 + delta + CLIPW];
      }
      const float e = __expf(x * 0.125f);
      stash[st][r] = (__bf16)e;
      ls += e;
    }
    *(bf16x4_t*)&eL[erow + st * 16 + 4 * g] = stash[st];
  }
  ls += __shfl_xor(ls, 16);
  ls += __shfl_xor(ls, 32);
  if (l < 16) redbuf[w * 16 + ql] = ls;
  __syncthreads();
  const float inv = 1.0f / (redbuf[ql] + redbuf[16 + ql] + redbuf[32 + ql] + redbuf[48 + ql]);
  if (l < 16) invL[w * 16 + l] = inv;

  // ---- bandP extraction (predicated, mostly skipped) ----
#pragma unroll
  for (int st = 0; st < 16; ++st) {
    const int s0t = sbase + st * 16;
    const bool near = (s0t + 15 >= q0 - CLIPW) && (s0t <= q0 + 15 + CLIPW);
    if (near) {
#pragma unroll
      for (int r = 0; r < 4; ++r) {
        const int delta = s0t + 4 * g + r - qabs;
        if ((unsigned)(delta + CLIPW) <= 2 * CLIPW)
          bandP[ql * 36 + delta + CLIPW] = (float)stash[st][r] * inv;
      }
    }
  }

  // ---- pass 2: PV + interleaved dense NT align stores (2 q-rows / iter) ----
  f32x4_t oacc[4] = {};
  const bf16* vfb = vfrag + (((size_t)bh * 32 + w * 8) * 4) * 512 + l * 8;
  float* abase = align_out + ((size_t)bh * TT + q0) * TT + sbase + l * 4;
#pragma unroll
  for (int i2 = 0; i2 < 8; ++i2) {
    const bf16x8_t pb = *(const bf16x8_t*)&eL[erow + i2 * 32 + 8 * g];
#pragma unroll
    for (int dt = 0; dt < 4; ++dt) {
      const bf16x8_t va = *(const bf16x8_t*)(vfb + ((size_t)i2 * 4 + dt) * 512);
      oacc[dt] = __builtin_amdgcn_mfma_f32_16x16x32_bf16(va, pb, oacc[dt], 0, 0, 0);
    }
#pragma unroll
    for (int qq = 0; qq < 2; ++qq) {
      const int q = i2 * 2 + qq;
      const float iq = invL[w * 16 + q];
      const bf16x4_t e4 = *(const bf16x4_t*)&eL[(w * 16 + q) * 264 + l * 4];
      f32x4_t p4;
      p4[0] = (float)e4[0] * iq;
      p4[1] = (float)e4[1] * iq;
      p4[2] = (float)e4[2] * iq;
      p4[3] = (float)e4[3] * iq;
      __builtin_nontemporal_store(p4, (f32x4_t*)(abase + (size_t)q * TT));
    }
  }
#pragma unroll
  for (int dt = 0; dt < 4; ++dt) {
    oacc[dt][0] *= inv; oacc[dt][1] *= inv;
    oacc[dt][2] *= inv; oacc[dt][3] *= inv;
  }

  // ---- all eL reads must complete block-wide before obuf overlays eL ----
  __syncthreads();

#pragma unroll
  for (int dt = 0; dt < 4; ++dt)
    *(f32x4_t*)&obuf[w * 1088 + ql * 68 + dt * 16 + 4 * g] = oacc[dt];
  __syncthreads();

  // ---- epilogue (wave 0): reduce + band-V MFMA + frag-layout attn store ----
  if (w == 0) {
    f32x4_t osum[4];
#pragma unroll
    for (int dt = 0; dt < 4; ++dt) {
      const int off = ql * 68 + dt * 16 + 4 * g;
      osum[dt] = *(const f32x4_t*)&obuf[off] + *(const f32x4_t*)&obuf[1088 + off] +
                 *(const f32x4_t*)&obuf[2176 + off] + *(const f32x4_t*)&obuf[3264 + off];
    }
    const f32x4_t b0 = *(const f32x4_t*)&bandP[ql * 36 + g * 8];
    const f32x4_t b1 = *(const f32x4_t*)&bandP[ql * 36 + g * 8 + 4];
    bf16x8_t pbb;
#pragma unroll
    for (int i = 0; i < 4; ++i) {
      pbb[i] = (__bf16)b0[i];
      pbb[4 + i] = (__bf16)b1[i];
    }
#pragma unroll
    for (int dt = 0; dt < 4; ++dt) {
      bf16x8_t wa;
#pragma unroll
      for (int jj = 0; jj < 8; ++jj) {
        const int j = g * 8 + jj;
        wa[jj] = (__bf16)((j < 9) ? wV[j * HD + dt * 16 + ql] : 0.f);
      }
      osum[dt] = __builtin_amdgcn_mfma_f32_16x16x32_bf16(wa, pbb, osum[dt], 0, 0, 0);
    }
#pragma unroll
    for (int dt = 0; dt < 4; ++dt)
#pragma unroll
      for (int r = 0; r < 4; ++r)
        stg[(dt * 16 + 4 * g + r) * 17 + ql] = osum[dt][r];
    // attnfrag write: ct global = h*2 + ctl, tt = q0>>4
#pragma unroll
    for (int ctl = 0; ctl < 2; ++ctl) {
      bf16x8_t p;
#pragma unroll
      for (int j = 0; j < 8; ++j)
        p[j] = (__bf16)stg[(ctl * 32 + g * 8 + j) * 17 + ql];
      *(bf16x8_t*)(attnfrag +
                   (((size_t)b * 64 + (q0 >> 4)) * 16 + h * 2 + ctl) * 512 + l * 8) = p;
    }
  }
}

extern "C" void kernel_launch(void* const* d_in, const int* in_sizes, int n_in,
                              void* d_out, int out_size, void* d_ws, size_t ws_size,
                              hipStream_t stream) {
  const float* X  = (const float*)d_in[0];
  const float* Wq = (const float*)d_in[1];
  const float* bq = (const float*)d_in[2];
  const float* Wk = (const float*)d_in[3];
  const float* bk = (const float*)d_in[4];
  const float* Wv = (const float*)d_in[5];
  const float* bv = (const float*)d_in[6];
  const float* Wp = (const float*)d_in[7];
  const float* bp = (const float*)d_in[8];
  const float* wK = (const float*)d_in[9];
  const float* wV = (const float*)d_in[10];

  float* out       = (float*)d_out;
  float* align_out = out + (size_t)BB * NCOUT * TT;

  const size_t SZ = (size_t)BB * HH * TT * HD;   // 4,194,304 elems (8 MB bf16)
  const size_t WF = 512 * 512;                    // 262,144 elems (0.5 MB bf16)
  bf16* qfrag    = (bf16*)d_ws;
  bf16* kfrag    = qfrag + SZ;
  bf16* vfrag    = qfrag + 2 * SZ;
  bf16* attnfrag = qfrag + 3 * SZ;
  bf16* xfrag    = qfrag + 4 * SZ;
  bf16* wqf      = qfrag + 5 * SZ;
  bf16* wkf      = wqf + WF;
  bf16* wvf      = wkf + WF;
  bf16* wpf      = wvf + WF;

  prep_w<<<dim3(128, 4), 256, 0, stream>>>(Wq, Wk, Wv, Wp, wqf, wkf, wvf, wpf);
  prep_x<<<dim3(2048), 256, 0, stream>>>(X, xfrag);
  gemm_qkv2<<<dim3(3072), 256, 0, stream>>>(
      xfrag, wqf, wkf, wvf, bq, bk, bv, qfrag, kfrag, vfrag);
  attn_v12<<<dim3(4096), 256, 0, stream>>>(
      qfrag, kfrag, vfrag, wK, wV, align_out, attnfrag);
  gemm_out2<<<dim3(1024), 256, 0, stream>>>(attnfrag, wpf, bp, out);
}